// Round 11
// baseline (183.278 us; speedup 1.0000x reference)
//
#include <hip/hip_runtime.h>

#define B_ 8
#define M_ 32
#define C_ 512
#define H_ 64
#define W_ 64
#define HW 4096
#define NKT 16
#define KC 32
// gcm tile
#define TW 4
#define TH 4
#define NPOS 16
#define PW 6
#define PH 6
#define NPM 36
// padded m grid
#define HP 66
#define WP 66
#define HPWP 4356

typedef __attribute__((ext_vector_type(8))) short short8;
typedef __attribute__((ext_vector_type(4))) float float4v;
typedef __attribute__((ext_vector_type(4))) unsigned uint4v;

static __device__ __forceinline__ unsigned pk_bf16(float lo, float hi) {
    unsigned r;
    asm("v_cvt_pk_bf16_f32 %0, %1, %2" : "=v"(r) : "v"(lo), "v"(hi));
    return r;
}

static __device__ __forceinline__ void load_lds16(const short* g, short* l) {
    __builtin_amdgcn_global_load_lds((const __attribute__((address_space(1))) void*)g,
                                     (__attribute__((address_space(3))) void*)l, 16, 0, 0);
}

// ---------- zero the norm accumulators (re-run every launch) ----------
__global__ void zero_norms(float* __restrict__ p) {
    int i = blockIdx.x * 256 + threadIdx.x;          // 160*256*4 = 163840 floats
    ((float4v*)p)[i] = (float4v){0.f, 0.f, 0.f, 0.f};
}

// ---------- prep v7: img-major layout -> streaming reads AND streaming writes ----------
// block = (img 40, kt 16, ph 2) = 1280 blocks. Reads 32 planes sequentially (8KB runs),
// writes 2048 consecutive 64B records (contiguous, modulo m-ring gaps).
__global__ __launch_bounds__(512)
void prep_kernel(const float* __restrict__ Q, const float* __restrict__ Mb,
                 short* __restrict__ qT, short* __restrict__ mT,
                 float* __restrict__ nq, float* __restrict__ nm) {
    __shared__ unsigned bufu[2][4096];   // [cp 16][pos 256] u32, 16 KB each
    __shared__ float    redf[2][2048];   // [w 8][pos 256] f32, 8 KB each

    const int tid = threadIdx.x;
    const int ii = blockIdx.x >> 5;          // 0..39
    const int kt = (blockIdx.x >> 1) & 15;
    const int ph = blockIdx.x & 1;
    const bool isq = (ii < B_);
    const int mi = ii - B_;
    const float* base = isq ? Q + (size_t)ii * C_ * HW : Mb + (size_t)mi * C_ * HW;

    const int l = tid & 63, w = tid >> 6;
    const float* lsrc = base + (size_t)(kt * 32 + 4 * w) * HW + ph * 2048 + l * 4;
    float* nrm = (isq ? nq + (size_t)ii * HW : nm + (size_t)mi * HW) + ph * 2048;

    float4v V0, V1, V2, V3;

#define LOADC(cc) { const float* p_ = lsrc + (cc) * 256; \
    V0 = *(const float4v*)(p_); \
    V1 = *(const float4v*)(p_ + HW); \
    V2 = *(const float4v*)(p_ + 2 * HW); \
    V3 = *(const float4v*)(p_ + 3 * HW); }

#define PACKW(bs) { \
    float4v s_ = V0 * V0 + V1 * V1 + V2 * V2 + V3 * V3; \
    uint4v a_, b_; \
    _Pragma("unroll") \
    for (int j = 0; j < 4; ++j) { a_[j] = pk_bf16(V0[j], V1[j]); b_[j] = pk_bf16(V2[j], V3[j]); } \
    *(uint4v*)&bufu[bs][(2 * w    ) * 256 + l * 4] = a_; \
    *(uint4v*)&bufu[bs][(2 * w + 1) * 256 + l * 4] = b_; \
    *(float4v*)&redf[bs][w * 256 + l * 4] = s_; }

#define GATHERST(cc, bs) { \
    _Pragma("unroll") \
    for (int it = 0; it < 2; ++it) { \
        int t_ = tid + it * 512; int rec = t_ >> 2, quad = t_ & 3; \
        union { unsigned u[4]; short8 s; } o_; \
        _Pragma("unroll") \
        for (int i = 0; i < 4; ++i) o_.u[i] = bufu[bs][(quad * 4 + i) * 256 + rec]; \
        int pos = ph * 2048 + (cc) * 256 + rec; \
        short* d_; \
        if (isq) d_ = qT + ((size_t)(ii * NKT + kt) * HW + pos) * KC + quad * 8; \
        else { int hh = pos >> 6, wc = pos & 63; \
               d_ = mT + ((size_t)(mi * NKT + kt) * HPWP + (size_t)(hh + 1) * WP + wc + 1) * KC + quad * 8; } \
        *(short8*)d_ = o_.s; } \
    if (tid < 256) { \
        float t_ = 0.f; \
        _Pragma("unroll") \
        for (int w2 = 0; w2 < 8; ++w2) t_ += redf[bs][w2 * 256 + tid]; \
        atomicAdd(nrm + (cc) * 256 + tid, t_); } }

    LOADC(0); PACKW(0); __syncthreads();
    #pragma unroll
    for (int cc = 0; cc < 8; ++cc) {
        if (cc < 7) LOADC(cc + 1);
        GATHERST(cc, cc & 1);
        if (cc < 7) PACKW((cc + 1) & 1);
        __syncthreads();
    }
#undef LOADC
#undef PACKW
#undef GATHERST

    // ---- m-blocks: zero this (mi, kt)'s halo-ring half (130 cells x 64 B) ----
    if (!isq) {
        short8 z = (short8){0, 0, 0, 0, 0, 0, 0, 0};
        for (int j = tid; j < 130 * 4; j += 512) {
            int cell = j >> 2, piece = j & 3;
            int pos2;
            if (cell < 66) pos2 = ph ? (65 * WP + cell) : cell;          // full row 0 / 65
            else {
                int k = cell - 66;                                        // side cols
                int row = (ph ? 33 : 1) + (k >> 1);
                pos2 = row * WP + ((k & 1) ? 65 : 0);
            }
            *(short8*)(mT + ((size_t)(mi * NKT + kt) * HPWP + pos2) * KC + piece * 8) = z;
        }
    }
}

// ---------- gcm: MFMA on raw bf16 (img-major staging), rsqrt epilogue ----------
__global__ __launch_bounds__(1024)
void gcm_kernel(const short* __restrict__ qT, const short* __restrict__ mT,
                const float* __restrict__ nq, const float* __restrict__ nm,
                float* __restrict__ out) {
    __shared__ __align__(16) short m_lds[NPM * M_ * KC];   // 72 KB
    __shared__ __align__(16) short q_lds[NPOS * 16 * KC];  // 16 KB

    const int tid = threadIdx.x;
    const int bx = blockIdx.x & 15, by = blockIdx.x >> 4;
    const int w0 = bx * TW, h0 = by * TH;
    const int wid = tid >> 6, lane = tid & 63;
    const int lw = wid & 3, lh = wid >> 2;
    const int col = lane & 15, kg = lane >> 4;
    const int mypos = lh * TW + lw;
    const int gh = h0 + lh, gw = w0 + lw;

    // per-lane m-record offsets for scattered global_load_lds staging
    const size_t MSTRIDE = (size_t)NKT * HPWP * KC;        // shorts per m image
    const size_t moff0 = (size_t)(lane >> 2) * MSTRIDE + (lane & 3) * 8;
    const size_t moff1 = moff0 + 16 * MSTRIDE;

    {
        short8 z = (short8){0, 0, 0, 0, 0, 0, 0, 0};
        *(short8*)&q_lds[tid * 8] = z;
    }

    float4v acc[9][2];
    #pragma unroll
    for (int d = 0; d < 9; ++d)
        #pragma unroll
        for (int hf = 0; hf < 2; ++hf)
            acc[d][hf] = (float4v){0.f, 0.f, 0.f, 0.f};

    for (int kt = 0; kt < NKT; ++kt) {
        __syncthreads();
        if (tid < 512) {
            int chunk = tid & 3, b = (tid >> 2) & 7, pidx = tid >> 5;
            int qh = h0 + (pidx >> 2), qw = w0 + (pidx & 3);
            const short* src = qT + ((size_t)(b * NKT + kt) * HW + qh * W_ + qw) * KC + chunk * 8;
            *(short8*)&q_lds[pidx * 512 + b * KC + chunk * 8] = *(const short8*)src;
        }
        for (int j = wid; j < NPM * 2; j += 16) {
            int pm = j >> 1, half = j & 1;
            int ph_ = pm / PW, pw_ = pm % PW;
            size_t pos2 = (size_t)(h0 + ph_) * WP + (w0 + pw_);
            const short* gsrc = mT + ((size_t)kt * HPWP + pos2) * KC + (half ? moff1 : moff0);
            short* ldst = m_lds + pm * 1024 + half * 512;
            load_lds16(gsrc, ldst);
        }
        __syncthreads();
        short8 aq = *(const short8*)&q_lds[mypos * 512 + col * KC + kg * 8];
        #pragma unroll
        for (int dh = 0; dh < 3; ++dh)
            #pragma unroll
            for (int dw = 0; dw < 3; ++dw) {
                const int pm = (lh + dh) * PW + (lw + dw);
                #pragma unroll
                for (int hf = 0; hf < 2; ++hf) {
                    short8 bm = *(const short8*)&m_lds[pm * 1024 + (hf * 16 + col) * KC + kg * 8];
                    acc[dh * 3 + dw][hf] =
                        __builtin_amdgcn_mfma_f32_16x16x32_bf16(aq, bm, acc[dh * 3 + dw][hf], 0, 0, 0);
                }
            }
    }

    float iq[4];
    #pragma unroll
    for (int r = 0; r < 4; ++r) {
        float ss = nq[(size_t)((kg & 1) * 4 + r) * HW + gh * W_ + gw];
        iq[r] = 1.0f / fmaxf(sqrtf(ss), 1e-12f);
    }
    float im[2][9];
    #pragma unroll
    for (int dh = 0; dh < 3; ++dh)
        #pragma unroll
        for (int dw = 0; dw < 3; ++dw) {
            int hh = min(63, max(0, gh + dh - 1));
            int ww = min(63, max(0, gw + dw - 1));
            #pragma unroll
            for (int hf = 0; hf < 2; ++hf) {
                float ss = nm[(size_t)(hf * 16 + col) * HW + hh * W_ + ww];
                im[hf][dh * 3 + dw] = 1.0f / fmaxf(sqrtf(ss), 1e-12f);
            }
        }
    float res[4];
    #pragma unroll
    for (int r = 0; r < 4; ++r) {
        float v0 = -1e30f, v1 = -1e30f;
        #pragma unroll
        for (int d = 0; d < 9; ++d) {
            v0 = fmaxf(v0, acc[d][0][r] * im[0][d]);
            v1 = fmaxf(v1, acc[d][1][r] * im[1][d]);
        }
        res[r] = fmaxf(v0 * iq[r], 0.f) + fmaxf(v1 * iq[r], 0.f);
    }
    #pragma unroll
    for (int mask = 1; mask < 16; mask <<= 1)
        #pragma unroll
        for (int r = 0; r < 4; ++r)
            res[r] += __shfl_xor(res[r], mask);

    if (col == 0 && kg < 2) {
        #pragma unroll
        for (int r = 0; r < 4; ++r) {
            int b = kg * 4 + r;
            out[(size_t)b * HW + gh * W_ + gw] = 1.0f - res[r] * (1.0f / M_);
        }
    }
}

extern "C" void kernel_launch(void* const* d_in, const int* in_sizes, int n_in,
                              void* d_out, int out_size, void* d_ws, size_t ws_size,
                              hipStream_t stream) {
    const float* Q  = (const float*)d_in[0];
    const float* Mb = (const float*)d_in[1];
    float* out = (float*)d_out;

    const size_t MT_SHORTS = (size_t)M_ * NKT * HPWP * KC;   // 71,368,704
    const size_t QT_SHORTS = (size_t)B_ * NKT * HW * KC;     // 16,777,216
    short* mT = (short*)d_ws;
    short* qT = mT + MT_SHORTS;
    float* nq = (float*)(qT + QT_SHORTS);                    // [8][4096]
    float* nm = nq + B_ * HW;                                // [32][4096]

    zero_norms<<<160, 256, 0, stream>>>(nq);                 // nq+nm contiguous
    prep_kernel<<<1280, 512, 0, stream>>>(Q, Mb, qT, mT, nq, nm);
    gcm_kernel<<<256, 1024, 0, stream>>>(qT, mT, nq, nm, out);
}

// Round 12
// 153.132 us; speedup vs baseline: 1.1969x; 1.1969x over previous
//
#include <hip/hip_runtime.h>

#define B_ 8
#define M_ 32
#define C_ 512
#define H_ 64
#define W_ 64
#define HW 4096
#define NKT 16
#define KC 32
#define CKG 128        // channels per prep block
// gcm tile
#define TW 4
#define TH 2
#define NPOS 8
#define PW 6
#define PH 4
#define NPM 24
// padded m grid
#define HP 66
#define WP 66
#define HPWP (HP*WP)

typedef __attribute__((ext_vector_type(8))) short short8;
typedef __attribute__((ext_vector_type(4))) float float4v;

static __device__ __forceinline__ unsigned pk_bf16(float lo, float hi) {
    unsigned r;
    asm("v_cvt_pk_bf16_f32 %0, %1, %2" : "=v"(r) : "v"(lo), "v"(hi));
    return r;
}

static __device__ __forceinline__ void load_lds16(const short* g, short* l) {
    __builtin_amdgcn_global_load_lds((const __attribute__((address_space(1))) void*)g,
                                     (__attribute__((address_space(3))) void*)l, 16, 0, 0);
}

// ---------- zero the norm-accumulator buffers (re-run every launch) ----------
__global__ void zero_norms(float* __restrict__ p) {
    int i = blockIdx.x * 256 + threadIdx.x;          // 160*256*4 = 163840 floats
    ((float4v*)p)[i] = (float4v){0.f, 0.f, 0.f, 0.f};
}

// ---------- prep v4 (best measured): c-split blocks for TLP, atomic norm partials ----------
// blocks 0..1023  : q (pr = g>>8 of 4,  h = (g>>2)&63, ktg = g&3)
// blocks 1024..5119: m (pr of 16, h, ktg)
__global__ __launch_bounds__(512, 8)
void prep_kernel(const float* __restrict__ Q, const float* __restrict__ Mb,
                 short* __restrict__ qT, short* __restrict__ mT,
                 float* __restrict__ nq, float* __restrict__ nm) {
    __shared__ unsigned buf[2][2176];   // 2 x 8704 B (u32 idx: img*1088 + w*17 + cpair)

    const int tid = threadIdx.x;
    const bool isq = (blockIdx.x < 1024);
    const int g  = isq ? (int)blockIdx.x : (int)blockIdx.x - 1024;
    const int pr  = g >> 8;
    const int h   = (g >> 2) & 63;
    const int ktg = g & 3;
    const float* base = (isq ? Q : Mb) + (size_t)(pr * 2) * C_ * HW + h * W_;

    // load/write roles
    const int w4 = tid & 15, cpair = (tid >> 4) & 15, limg = tid >> 8;
    const float* lsrc = base + (size_t)limg * C_ * HW + (size_t)(ktg * CKG + cpair * 2) * HW + w4 * 4;
    unsigned* wA = &buf[0][limg * 1088 + cpair];
    unsigned* wB = &buf[1][limg * 1088 + cpair];
    // gather/store roles
    const int ckq = tid & 3, rimg = (tid >> 2) & 1, rw = tid >> 3;
    const unsigned* rA = &buf[0][rimg * 1088 + rw * 17 + ckq * 4];
    const unsigned* rB = &buf[1][rimg * 1088 + rw * 17 + ckq * 4];

    float4v ssq = {0.f, 0.f, 0.f, 0.f};
    float4v a0, a1, b0, b1, c0, c1, d0, d1;

#define LOADP(ch, r0, r1) { const float* p_ = lsrc + (size_t)(ch) * 32 * HW; \
                            r0 = *(const float4v*)p_; r1 = *(const float4v*)(p_ + HW); }
#define WRITEP(wb, r0, r1) { ssq += r0 * r0 + r1 * r1; \
    wb[(w4*4+0)*17] = pk_bf16(r0[0], r1[0]); wb[(w4*4+1)*17] = pk_bf16(r0[1], r1[1]); \
    wb[(w4*4+2)*17] = pk_bf16(r0[2], r1[2]); wb[(w4*4+3)*17] = pk_bf16(r0[3], r1[3]); }
#define STOREP(ch, rb) { union { unsigned u[4]; short8 s; } o_; \
    o_.u[0] = rb[0]; o_.u[1] = rb[1]; o_.u[2] = rb[2]; o_.u[3] = rb[3]; \
    const int kt_ = ktg * 4 + (ch); short* dst_; \
    if (isq) dst_ = qT + (((size_t)kt_ * HW + h * 64 + rw) * B_ + pr * 2 + rimg) * KC + ckq * 8; \
    else     dst_ = mT + (((size_t)kt_ * HPWP + (size_t)(h + 1) * WP + rw + 1) * M_ + pr * 2 + rimg) * KC + ckq * 8; \
    *(short8*)dst_ = o_.s; }

    LOADP(0, a0, a1);
    WRITEP(wA, a0, a1);            // chunk0 -> buf0
    LOADP(1, b0, b1);
    __syncthreads();
    // segment 0: consume ch0 (buf0), stage ch1 (buf1)
    LOADP(2, c0, c1);
    STOREP(0, rA);
    WRITEP(wB, b0, b1);
    __syncthreads();
    // segment 1: consume ch1 (buf1), stage ch2 (buf0)
    LOADP(3, d0, d1);
    STOREP(1, rB);
    WRITEP(wA, c0, c1);
    __syncthreads();
    // segment 2: consume ch2 (buf0), stage ch3 (buf1)
    STOREP(2, rA);
    WRITEP(wB, d0, d1);
    __syncthreads();
    // segment 3: consume ch3 (buf1); stage norm partials into buf0
    STOREP(3, rB);
    float* red = (float*)&buf[0][0];  // 2048 f32 = 8 KB
    *(float4v*)&red[(limg * 16 + cpair) * 64 + w4 * 4] = ssq;
    __syncthreads();

    if (tid < 128) {
        int im_ = tid >> 6, w = tid & 63;
        float t = 0.f;
        #pragma unroll
        for (int cp = 0; cp < 16; ++cp) t += red[(im_ * 16 + cp) * 64 + w];
        atomicAdd(&(isq ? nq : nm)[(size_t)(pr * 2 + im_) * HW + h * 64 + w], t);
    }

    // ---- m-blocks: zero halo-ring slices (this block's 4 kt, its pr 128B slice) ----
    if (!isq) {
        short8 z = (short8){0, 0, 0, 0, 0, 0, 0, 0};
        if (tid < 64) {                      // cols 0 & 65 of row h+1, kts of this ktg
            int e = tid & 7, kk = (tid >> 3) & 3, c = tid >> 5;
            int kt = ktg * 4 + kk;
            *(short8*)(mT + ((size_t)kt * HPWP + (size_t)(h + 1) * WP + (c ? 65 : 0)) * (M_ * KC)
                       + pr * 64 + e * 8) = z;
        }
        if (h == 0 || h == 63) {             // full rows 0 / 65 for this ktg
            int row = (h == 0) ? 0 : 65;
            for (int j = tid; j < 66 * 4 * 8; j += 512) {
                int e = j & 7, kk = (j >> 3) & 3, cell = j >> 5;
                int kt = ktg * 4 + kk;
                *(short8*)(mT + ((size_t)kt * HPWP + (size_t)row * WP + cell) * (M_ * KC)
                           + pr * 64 + e * 8) = z;
            }
        }
    }
#undef LOADP
#undef WRITEP
#undef STOREP
}

// ---------- gcm v2: 4x2 tile, 512 blocks (all CUs), rsqrt epilogue ----------
__global__ __launch_bounds__(512)
void gcm_kernel(const short* __restrict__ qT, const short* __restrict__ mT,
                const float* __restrict__ nq, const float* __restrict__ nm,
                float* __restrict__ out) {
    __shared__ __align__(16) short m_lds[NPM * M_ * KC];   // 48 KB
    __shared__ __align__(16) short q_lds[NPOS * 16 * KC];  // 8 KB

    const int tid = threadIdx.x;
    const int bx = blockIdx.x & 15, by = blockIdx.x >> 4;   // by 0..31
    const int w0 = bx * TW, h0 = by * TH;
    const int wid = tid >> 6, lane = tid & 63;
    const int lw = wid & 3, lh = wid >> 2;                  // lh 0..1
    const int col = lane & 15, kg = lane >> 4;
    const int mypos = lh * TW + lw;
    const int gh = h0 + lh, gw = w0 + lw;

    {
        short8 z = (short8){0, 0, 0, 0, 0, 0, 0, 0};
        *(short8*)&q_lds[tid * 8] = z;   // 512 thr x 8 = 4096 shorts = full q_lds
    }

    float4v acc[9][2];
    #pragma unroll
    for (int d = 0; d < 9; ++d)
        #pragma unroll
        for (int hf = 0; hf < 2; ++hf)
            acc[d][hf] = (float4v){0.f, 0.f, 0.f, 0.f};

    for (int kt = 0; kt < NKT; ++kt) {
        __syncthreads();
        if (tid < 256) {
            int chunk = tid & 3, b = (tid >> 2) & 7, pidx = tid >> 5;   // pidx 0..7
            int qh = h0 + (pidx >> 2), qw = w0 + (pidx & 3);
            const short* src = qT + (((size_t)kt * HW + qh * W_ + qw) * B_ + b) * KC + chunk * 8;
            *(short8*)&q_lds[pidx * 512 + b * KC + chunk * 8] = *(const short8*)src;
        }
        for (int j = wid; j < NPM * 2; j += 8) {
            int pm = j >> 1, half = j & 1;
            int ph = pm / PW, pw = pm % PW;
            size_t pos2 = (size_t)(h0 + ph) * WP + (w0 + pw);
            const short* gsrc = mT + ((size_t)kt * HPWP + pos2) * (M_ * KC)
                              + half * 512 + (size_t)lane * 8;
            short* ldst = m_lds + pm * 1024 + half * 512;
            load_lds16(gsrc, ldst);
        }
        __syncthreads();
        short8 aq = *(const short8*)&q_lds[mypos * 512 + col * KC + kg * 8];
        #pragma unroll
        for (int dh = 0; dh < 3; ++dh)
            #pragma unroll
            for (int dw = 0; dw < 3; ++dw) {
                const int pm = (lh + dh) * PW + (lw + dw);
                #pragma unroll
                for (int hf = 0; hf < 2; ++hf) {
                    short8 bm = *(const short8*)&m_lds[pm * 1024 + (hf * 16 + col) * KC + kg * 8];
                    acc[dh * 3 + dw][hf] =
                        __builtin_amdgcn_mfma_f32_16x16x32_bf16(aq, bm, acc[dh * 3 + dw][hf], 0, 0, 0);
                }
            }
    }

    float iq[4];
    #pragma unroll
    for (int r = 0; r < 4; ++r) {
        float ss = nq[(size_t)((kg & 1) * 4 + r) * HW + gh * W_ + gw];
        iq[r] = 1.0f / fmaxf(sqrtf(ss), 1e-12f);
    }
    float im[2][9];
    #pragma unroll
    for (int dh = 0; dh < 3; ++dh)
        #pragma unroll
        for (int dw = 0; dw < 3; ++dw) {
            int hh = min(63, max(0, gh + dh - 1));
            int ww = min(63, max(0, gw + dw - 1));
            #pragma unroll
            for (int hf = 0; hf < 2; ++hf) {
                float ss = nm[(size_t)(hf * 16 + col) * HW + hh * W_ + ww];
                im[hf][dh * 3 + dw] = 1.0f / fmaxf(sqrtf(ss), 1e-12f);
            }
        }
    float res[4];
    #pragma unroll
    for (int r = 0; r < 4; ++r) {
        float v0 = -1e30f, v1 = -1e30f;
        #pragma unroll
        for (int d = 0; d < 9; ++d) {
            v0 = fmaxf(v0, acc[d][0][r] * im[0][d]);
            v1 = fmaxf(v1, acc[d][1][r] * im[1][d]);
        }
        res[r] = fmaxf(v0 * iq[r], 0.f) + fmaxf(v1 * iq[r], 0.f);
    }
    #pragma unroll
    for (int mask = 1; mask < 16; mask <<= 1)
        #pragma unroll
        for (int r = 0; r < 4; ++r)
            res[r] += __shfl_xor(res[r], mask);

    if (col == 0 && kg < 2) {
        #pragma unroll
        for (int r = 0; r < 4; ++r) {
            int b = kg * 4 + r;
            out[(size_t)b * HW + gh * W_ + gw] = 1.0f - res[r] * (1.0f / M_);
        }
    }
}

extern "C" void kernel_launch(void* const* d_in, const int* in_sizes, int n_in,
                              void* d_out, int out_size, void* d_ws, size_t ws_size,
                              hipStream_t stream) {
    const float* Q  = (const float*)d_in[0];
    const float* Mb = (const float*)d_in[1];
    float* out = (float*)d_out;

    const size_t MT_SHORTS = (size_t)NKT * HPWP * M_ * KC;   // 71,368,704
    const size_t QT_SHORTS = (size_t)NKT * HW * B_ * KC;     // 16,777,216
    short* mT = (short*)d_ws;
    short* qT = mT + MT_SHORTS;
    float* nq = (float*)(qT + QT_SHORTS);
    float* nm = nq + B_ * HW;

    zero_norms<<<160, 256, 0, stream>>>(nq);                 // nq+nm contiguous 163840 f32
    prep_kernel<<<5120, 512, 0, stream>>>(Q, Mb, qT, mT, nq, nm);
    gcm_kernel<<<512, 512, 0, stream>>>(qT, mT, nq, nm, out);
}